// Round 12
// baseline (139.526 us; speedup 1.0000x reference)
//
#include <hip/hip_runtime.h>
#include <hip/hip_bf16.h>
#include <hip/hip_fp16.h>

typedef __attribute__((ext_vector_type(8))) short bf16x8;
typedef __attribute__((ext_vector_type(4))) float f32x4;

#define NB 8
#define NPIX 65536
#define NC 64
#define CC 4096
#define HIN 16
#define HHID 64
#define LN_EPS 1e-5f

#define BPB 64           // kv pass: 512 blocks total = exactly 2/CU, one round
#define PPBLK (NPIX/BPB) // 1024 px per kv block
#define PPW (PPBLK/4)    // 256 px per kv wave -> 8 chunks of 32
#define NCH (PPW/32)

#define QBPB 256           // q pass: 2048 blocks = exactly 8/CU at 64-VGPR cap
#define QPPB (NPIX/QBPB)   // 256 px per q block
#define QPPW (QPPB/4)      // 64 px per q wave -> 4 tiles of 16

static __device__ __forceinline__ short f2bf(float f) {
    union { __hip_bfloat16 h; short s; } u;
    u.h = __float2bfloat16(f);
    return u.s;
}

// ---------------- hypernetwork: w = (gelu(p@w1+b1))@w2 + b2 ----------------
__global__ void hyper_mlp_kernel(
    const float* __restrict__ p,
    const float* __restrict__ qw1, const float* __restrict__ qb1,
    const float* __restrict__ qw2, const float* __restrict__ qb2,
    const float* __restrict__ kw1, const float* __restrict__ kb1,
    const float* __restrict__ kw2, const float* __restrict__ kb2,
    const float* __restrict__ vw1, const float* __restrict__ vb1,
    const float* __restrict__ vw2, const float* __restrict__ vb2,
    float* __restrict__ wq,     // [NB][CC] fp32
    short* __restrict__ wkvt,   // [NB][128][64] bf16 bits
    float* __restrict__ xkv)    // [NB][1024] zeroed here
{
    const int chunk = blockIdx.x;
    const int proj  = blockIdx.y;
    const int b     = blockIdx.z;
    const float* w1 = (proj == 0) ? qw1 : (proj == 1) ? kw1 : vw1;
    const float* b1 = (proj == 0) ? qb1 : (proj == 1) ? kb1 : vb1;
    const float* w2 = (proj == 0) ? qw2 : (proj == 1) ? kw2 : vw2;
    const float* b2 = (proj == 0) ? qb2 : (proj == 1) ? kb2 : vb2;

    __shared__ float hsh[HHID];
    const int t = threadIdx.x;
    if (t < HHID) {
        float a = b1[t];
        #pragma unroll
        for (int i = 0; i < HIN; ++i) a = fmaf(p[b*HIN + i], w1[i*HHID + t], a);
        float x3 = a * a * a;
        float inner = 0.7978845608028654f * (a + 0.044715f * x3);
        hsh[t] = 0.5f * a * (1.0f + tanhf(inner));
    }
    if (proj == 1 && chunk == 0) {
        #pragma unroll
        for (int i = 0; i < 4; ++i) xkv[(size_t)b*1024 + t + 256*i] = 0.f;
    }
    __syncthreads();
    #pragma unroll
    for (int r = 0; r < 2; ++r) {
        int o = chunk*512 + t + 256*r;   // o = cin*64 + cout
        float a = b2[o];
        for (int j = 0; j < HHID; ++j) a = fmaf(hsh[j], w2[j*CC + o], a);
        int cin = o >> 6, cout = o & 63;
        if (proj == 0) {
            wq[(size_t)b*CC + o] = a;
        } else {
            int row = (proj == 1) ? cout : 64 + cout;
            wkvt[((size_t)b*128 + row)*64 + cin] = f2bf(a);
        }
    }
}

// ---------------- pass 1: K,V projection (MFMA) + LN + Xkv (MFMA) ----------------
__global__ __launch_bounds__(256, 2) void kv_kernel(
    const float* __restrict__ X,      // [NB][NPIX][64]
    const short* __restrict__ wkvt,   // [NB][128][64] bf16
    const float* __restrict__ lnk_g,
    const float* __restrict__ lnk_b,
    float* __restrict__ xkv)          // [NB][4][16][16] fp32, atomically accumulated
{
    const int bb = blockIdx.x, b = blockIdx.y;
    const int t = threadIdx.x, wave = t >> 6, lane = t & 63;
    const int l4 = lane >> 4, l15 = lane & 15;

    bf16x8 bw[2][8];
    #pragma unroll
    for (int s = 0; s < 2; ++s)
        #pragma unroll
        for (int nt = 0; nt < 8; ++nt) {
            const short* pw = wkvt + (((size_t)b*128 + nt*16 + l15)*64 + s*32 + l4*8);
            bw[s][nt] = *(const bf16x8*)pw;
        }

    float g[4], be[4];
    #pragma unroll
    for (int nt = 0; nt < 4; ++nt) {
        g[nt]  = lnk_g[nt*16 + l15];
        be[nt] = lnk_b[nt*16 + l15];
    }

    f32x4 kv[4];
    #pragma unroll
    for (int h = 0; h < 4; ++h) kv[h] = (f32x4){0.f,0.f,0.f,0.f};

    const float* Xw = X + ((size_t)b*NPIX + (size_t)bb*PPBLK + wave*PPW)*64;

    auto loadch = [&](float (&xf)[2][2][8], int ci) {
        const float* Xc = Xw + (size_t)ci*32*64;
        #pragma unroll
        for (int t2 = 0; t2 < 2; ++t2)
            #pragma unroll
            for (int s = 0; s < 2; ++s) {
                const float* px = Xc + (t2*16 + l15)*64 + s*32 + l4*8;
                *(float4*)&xf[t2][s][0] = *(const float4*)px;
                *(float4*)&xf[t2][s][4] = *(const float4*)(px + 4);
            }
    };

    auto process = [&](float (&xf)[2][2][8]) {
        bf16x8 af[2][2];
        #pragma unroll
        for (int t2 = 0; t2 < 2; ++t2)
            #pragma unroll
            for (int s = 0; s < 2; ++s)
                #pragma unroll
                for (int j = 0; j < 8; ++j) af[t2][s][j] = f2bf(xf[t2][s][j]);

        f32x4 acc[2][8];
        #pragma unroll
        for (int t2 = 0; t2 < 2; ++t2)
            #pragma unroll
            for (int nt = 0; nt < 8; ++nt) acc[t2][nt] = (f32x4){0.f,0.f,0.f,0.f};
        #pragma unroll
        for (int s = 0; s < 2; ++s)
            #pragma unroll
            for (int t2 = 0; t2 < 2; ++t2)
                #pragma unroll
                for (int nt = 0; nt < 8; ++nt)
                    acc[t2][nt] = __builtin_amdgcn_mfma_f32_16x16x32_bf16(
                        af[t2][s], bw[s][nt], acc[t2][nt], 0, 0, 0);

        // LN stats packed as fp16 pairs (sk,sv),(qk,qv): 2 packed reduces.
        __half2 hs[2][4], hq[2][4];
        #pragma unroll
        for (int t2 = 0; t2 < 2; ++t2)
            #pragma unroll
            for (int r = 0; r < 4; ++r) {
                float a0 = acc[t2][0][r], a1 = acc[t2][1][r], a2 = acc[t2][2][r], a3 = acc[t2][3][r];
                float b0 = acc[t2][4][r], b1 = acc[t2][5][r], b2 = acc[t2][6][r], b3 = acc[t2][7][r];
                hs[t2][r] = __floats2half2_rn((a0+a1)+(a2+a3), (b0+b1)+(b2+b3));
                hq[t2][r] = __floats2half2_rn((a0*a0+a1*a1)+(a2*a2+a3*a3),
                                              (b0*b0+b1*b1)+(b2*b2+b3*b3));
            }
        #pragma unroll
        for (int off = 1; off < 16; off <<= 1) {
            #pragma unroll
            for (int t2 = 0; t2 < 2; ++t2)
                #pragma unroll
                for (int r = 0; r < 4; ++r) {
                    int v1 = *(int*)&hs[t2][r];
                    v1 = __shfl_xor(v1, off);
                    hs[t2][r] = __hadd2(hs[t2][r], *(__half2*)&v1);
                    int v2 = *(int*)&hq[t2][r];
                    v2 = __shfl_xor(v2, off);
                    hq[t2][r] = __hadd2(hq[t2][r], *(__half2*)&v2);
                }
        }

        bf16x8 ka[4], va[4];
        #pragma unroll
        for (int t2 = 0; t2 < 2; ++t2)
            #pragma unroll
            for (int r = 0; r < 4; ++r) {
                float mk = __low2float(hs[t2][r])  * (1.f/NC);
                float mv = __high2float(hs[t2][r]) * (1.f/NC);
                float rk = rsqrtf(__low2float(hq[t2][r]) *(1.f/NC) - mk*mk + LN_EPS);
                float rv = rsqrtf(__high2float(hq[t2][r])*(1.f/NC) - mv*mv + LN_EPS);
                #pragma unroll
                for (int nt = 0; nt < 4; ++nt) {
                    // faithful: BOTH k and v normalized with lnk params
                    ka[nt][t2*4+r] = f2bf((acc[t2][nt  ][r] - mk)*rk*g[nt] + be[nt]);
                    va[nt][t2*4+r] = f2bf((acc[t2][nt+4][r] - mv)*rv*g[nt] + be[nt]);
                }
            }
        #pragma unroll
        for (int h = 0; h < 4; ++h)
            kv[h] = __builtin_amdgcn_mfma_f32_16x16x32_bf16(ka[h], va[h], kv[h], 0, 0, 0);
    };

    // software pipeline: prefetch next chunk's loads only (NCH = 8, even)
    float xfA[2][2][8], xfB[2][2][8];
    loadch(xfA, 0);
    #pragma unroll 1
    for (int ch = 0; ch < NCH; ch += 2) {
        loadch(xfB, ch + 1);
        process(xfA);
        if (ch + 2 < NCH) loadch(xfA, ch + 2);
        process(xfB);
    }

    __shared__ float red[4][1024];
    #pragma unroll
    for (int h = 0; h < 4; ++h)
        #pragma unroll
        for (int r = 0; r < 4; ++r)
            red[wave][(h*4+r)*64 + lane] = kv[h][r];
    __syncthreads();
    for (int idx = t; idx < 1024; idx += 256) {
        float s = red[0][idx] + red[1][idx] + red[2][idx] + red[3][idx];
        int ln = idx & 63, hr = idx >> 6;
        int h = hr >> 2, r = hr & 3;
        int d = (ln >> 4)*4 + r, e = ln & 15;
        atomicAdd(&xkv[(size_t)b*1024 + h*256 + d*16 + e], s);
    }
}

// -------- fold: W~[och=e*4+h][cin] = sum_d wq[cin][h*16+d]*Xkv[h][d][e]/NPIX --------
__global__ void fold_kernel(const float* __restrict__ wq,
                            const float* __restrict__ xkv,
                            short* __restrict__ wft)   // [NB][64 och][64 cin] bf16
{
    const int c4 = blockIdx.x, b = blockIdx.y, t = threadIdx.x;
    #pragma unroll
    for (int i = 0; i < 4; ++i) {
        int idx = c4*1024 + t + 256*i;
        int och = idx >> 6, c = idx & 63;
        int h = och & 3, e = och >> 2;
        float s = 0.f;
        #pragma unroll
        for (int d = 0; d < 16; ++d)
            s += wq[(size_t)b*CC + c*64 + h*16 + d] * xkv[(size_t)b*1024 + h*256 + d*16 + e];
        wft[((size_t)b*64 + och)*64 + c] = f2bf(s * (1.f/65536.f));
    }
}

// ------- pass 2: out = X · W~^T  (8 blocks/CU TLP streamer, 1-ahead ping-pong,
//         row=pixel D-layout -> sector-contiguous scalar stores) -------
__global__ __launch_bounds__(256, 8) void q_kernel(
    const float* __restrict__ X,     // [NB][NPIX][64]
    const short* __restrict__ wft,   // [NB][64][64] bf16 ([och][cin])
    float* __restrict__ out)         // [NB][NPIX][64]
{
    const int bb = blockIdx.x, b = blockIdx.y;
    const int t = threadIdx.x, wave = t >> 6, lane = t & 63;
    const int l4 = lane >> 4, l15 = lane & 15;

    // W~ frags, reused as B-operand (k-major along j):
    // b[j] = W~^T[cin = s*32+l4*8+j][och = nt*16 + l15]  (L2-hot, loaded once)
    bf16x8 aw[2][4];
    #pragma unroll
    for (int s = 0; s < 2; ++s)
        #pragma unroll
        for (int nt = 0; nt < 4; ++nt)
            aw[s][nt] = *(const bf16x8*)&wft[((size_t)b*64 + nt*16 + l15)*64 + s*32 + l4*8];

    const size_t pixbase = (size_t)b*NPIX + (size_t)bb*QPPB + wave*QPPW;
    const float* Xw = X + pixbase*64;
    float* Ob = out + pixbase*64;

    float4 A0, A1, A2, A3, B0, B1, B2, B3;

    auto LD = [&](float4& x0, float4& x1, float4& x2, float4& x3, int tp) {
        const float* p0 = Xw + (size_t)(tp*16 + l15)*64 + l4*8;
        x0 = *(const float4*)p0;        x1 = *(const float4*)(p0 + 4);
        x2 = *(const float4*)(p0 + 32); x3 = *(const float4*)(p0 + 36);
    };
    auto PR = [&](float4& x0, float4& x1, float4& x2, float4& x3, int tp) {
        bf16x8 bx0, bx1;   // A-frags: a[j] = X[px=l15][cin = s*32 + l4*8 + j]
        #pragma unroll
        for (int j = 0; j < 4; ++j) {
            bx0[j]   = f2bf(x0[j]);  bx0[4+j] = f2bf(x1[j]);
            bx1[j]   = f2bf(x2[j]);  bx1[4+j] = f2bf(x3[j]);
        }
        f32x4 acc[4];
        #pragma unroll
        for (int nt = 0; nt < 4; ++nt) acc[nt] = (f32x4){0.f,0.f,0.f,0.f};
        // A=X, B=W~^T: D[m=px][n=och] -> lane holds px=l4*4+r, och=nt*16+l15
        #pragma unroll
        for (int nt = 0; nt < 4; ++nt)
            acc[nt] = __builtin_amdgcn_mfma_f32_16x16x32_bf16(bx0, aw[0][nt], acc[nt], 0, 0, 0);
        #pragma unroll
        for (int nt = 0; nt < 4; ++nt)
            acc[nt] = __builtin_amdgcn_mfma_f32_16x16x32_bf16(bx1, aw[1][nt], acc[nt], 0, 0, 0);
        // scalar stores: lanes l15=0..15 complete a contiguous 64B sector per
        // instruction (round-3 pattern: WRITE_SIZE == output size)
        #pragma unroll
        for (int nt = 0; nt < 4; ++nt)
            #pragma unroll
            for (int r = 0; r < 4; ++r)
                Ob[(size_t)(tp*16 + l4*4 + r)*64 + nt*16 + l15] = acc[nt][r];
    };

    // 4 tiles, 1-ahead static ping-pong (TLP at 32 waves/CU hides the rest)
    LD(A0,A1,A2,A3, 0);
    LD(B0,B1,B2,B3, 1);  PR(A0,A1,A2,A3, 0);
    LD(A0,A1,A2,A3, 2);  PR(B0,B1,B2,B3, 1);
    LD(B0,B1,B2,B3, 3);  PR(A0,A1,A2,A3, 2);
    PR(B0,B1,B2,B3, 3);
}

extern "C" void kernel_launch(void* const* d_in, const int* in_sizes, int n_in,
                              void* d_out, int out_size, void* d_ws, size_t ws_size,
                              hipStream_t stream) {
    const float* X    = (const float*)d_in[0];
    const float* p    = (const float*)d_in[1];
    const float* qw1  = (const float*)d_in[2];
    const float* qb1  = (const float*)d_in[3];
    const float* qw2  = (const float*)d_in[4];
    const float* qb2  = (const float*)d_in[5];
    const float* kw1  = (const float*)d_in[6];
    const float* kb1  = (const float*)d_in[7];
    const float* kw2  = (const float*)d_in[8];
    const float* kb2  = (const float*)d_in[9];
    const float* vw1  = (const float*)d_in[10];
    const float* vb1  = (const float*)d_in[11];
    const float* vw2  = (const float*)d_in[12];
    const float* vb2  = (const float*)d_in[13];
    const float* lnkg = (const float*)d_in[14];
    const float* lnkb = (const float*)d_in[15];

    float* out  = (float*)d_out;
    float* wq   = (float*)d_ws;                       // NB*CC fp32
    float* xkv  = wq + (size_t)NB*CC;                 // NB*1024 fp32
    short* wkvt = (short*)(xkv + (size_t)NB*1024);    // NB*128*64 bf16
    short* wft  = wkvt + (size_t)NB*128*64;           // NB*64*64 bf16

    hyper_mlp_kernel<<<dim3(8, 3, NB), 256, 0, stream>>>(
        p, qw1,qb1,qw2,qb2, kw1,kb1,kw2,kb2, vw1,vb1,vw2,vb2, wq, wkvt, xkv);
    kv_kernel<<<dim3(BPB, NB), 256, 0, stream>>>(X, wkvt, lnkg, lnkb, xkv);
    fold_kernel<<<dim3(4, NB), 256, 0, stream>>>(wq, xkv, wft);
    q_kernel<<<dim3(QBPB, NB), 256, 0, stream>>>(X, wft, out);
}

// Round 13
// 91.467 us; speedup vs baseline: 1.5254x; 1.5254x over previous
//
#include <hip/hip_runtime.h>
#include <hip/hip_bf16.h>
#include <hip/hip_fp16.h>

typedef __attribute__((ext_vector_type(8))) short bf16x8;
typedef __attribute__((ext_vector_type(4))) float f32x4;

#define NB 8
#define NPIX 65536
#define NC 64
#define CC 4096
#define HIN 16
#define HHID 64
#define LN_EPS 1e-5f

#define BPB 64           // kv pass: 512 blocks total = exactly 2/CU, one round
#define PPBLK (NPIX/BPB) // 1024 px per kv block
#define PPW (PPBLK/4)    // 256 px per kv wave -> 8 chunks of 32
#define NCH (PPW/32)

#define QBPB 128           // q pass: 1024 blocks = exactly 4/CU, one uniform round
#define QPPB (NPIX/QBPB)   // 512 px per q block
#define QPPW (QPPB/4)      // 128 px per q wave -> 8 tiles of 16

static __device__ __forceinline__ short f2bf(float f) {
    union { __hip_bfloat16 h; short s; } u;
    u.h = __float2bfloat16(f);
    return u.s;
}

// ---------------- hypernetwork: w = (gelu(p@w1+b1))@w2 + b2 ----------------
__global__ void hyper_mlp_kernel(
    const float* __restrict__ p,
    const float* __restrict__ qw1, const float* __restrict__ qb1,
    const float* __restrict__ qw2, const float* __restrict__ qb2,
    const float* __restrict__ kw1, const float* __restrict__ kb1,
    const float* __restrict__ kw2, const float* __restrict__ kb2,
    const float* __restrict__ vw1, const float* __restrict__ vb1,
    const float* __restrict__ vw2, const float* __restrict__ vb2,
    float* __restrict__ wq,     // [NB][CC] fp32
    short* __restrict__ wkvt,   // [NB][128][64] bf16 bits
    float* __restrict__ xkv)    // [NB][1024] zeroed here
{
    const int chunk = blockIdx.x;
    const int proj  = blockIdx.y;
    const int b     = blockIdx.z;
    const float* w1 = (proj == 0) ? qw1 : (proj == 1) ? kw1 : vw1;
    const float* b1 = (proj == 0) ? qb1 : (proj == 1) ? kb1 : vb1;
    const float* w2 = (proj == 0) ? qw2 : (proj == 1) ? kw2 : vw2;
    const float* b2 = (proj == 0) ? qb2 : (proj == 1) ? kb2 : vb2;

    __shared__ float hsh[HHID];
    const int t = threadIdx.x;
    if (t < HHID) {
        float a = b1[t];
        #pragma unroll
        for (int i = 0; i < HIN; ++i) a = fmaf(p[b*HIN + i], w1[i*HHID + t], a);
        float x3 = a * a * a;
        float inner = 0.7978845608028654f * (a + 0.044715f * x3);
        hsh[t] = 0.5f * a * (1.0f + tanhf(inner));
    }
    if (proj == 1 && chunk == 0) {
        #pragma unroll
        for (int i = 0; i < 4; ++i) xkv[(size_t)b*1024 + t + 256*i] = 0.f;
    }
    __syncthreads();
    #pragma unroll
    for (int r = 0; r < 2; ++r) {
        int o = chunk*512 + t + 256*r;   // o = cin*64 + cout
        float a = b2[o];
        for (int j = 0; j < HHID; ++j) a = fmaf(hsh[j], w2[j*CC + o], a);
        int cin = o >> 6, cout = o & 63;
        if (proj == 0) {
            wq[(size_t)b*CC + o] = a;
        } else {
            int row = (proj == 1) ? cout : 64 + cout;
            wkvt[((size_t)b*128 + row)*64 + cin] = f2bf(a);
        }
    }
}

// ---------------- pass 1: K,V projection (MFMA) + LN + Xkv (MFMA) ----------------
__global__ __launch_bounds__(256, 2) void kv_kernel(
    const float* __restrict__ X,      // [NB][NPIX][64]
    const short* __restrict__ wkvt,   // [NB][128][64] bf16
    const float* __restrict__ lnk_g,
    const float* __restrict__ lnk_b,
    float* __restrict__ xkv)          // [NB][4][16][16] fp32, atomically accumulated
{
    const int bb = blockIdx.x, b = blockIdx.y;
    const int t = threadIdx.x, wave = t >> 6, lane = t & 63;
    const int l4 = lane >> 4, l15 = lane & 15;

    bf16x8 bw[2][8];
    #pragma unroll
    for (int s = 0; s < 2; ++s)
        #pragma unroll
        for (int nt = 0; nt < 8; ++nt) {
            const short* pw = wkvt + (((size_t)b*128 + nt*16 + l15)*64 + s*32 + l4*8);
            bw[s][nt] = *(const bf16x8*)pw;
        }

    float g[4], be[4];
    #pragma unroll
    for (int nt = 0; nt < 4; ++nt) {
        g[nt]  = lnk_g[nt*16 + l15];
        be[nt] = lnk_b[nt*16 + l15];
    }

    f32x4 kv[4];
    #pragma unroll
    for (int h = 0; h < 4; ++h) kv[h] = (f32x4){0.f,0.f,0.f,0.f};

    const float* Xw = X + ((size_t)b*NPIX + (size_t)bb*PPBLK + wave*PPW)*64;

    auto loadch = [&](float (&xf)[2][2][8], int ci) {
        const float* Xc = Xw + (size_t)ci*32*64;
        #pragma unroll
        for (int t2 = 0; t2 < 2; ++t2)
            #pragma unroll
            for (int s = 0; s < 2; ++s) {
                const float* px = Xc + (t2*16 + l15)*64 + s*32 + l4*8;
                *(float4*)&xf[t2][s][0] = *(const float4*)px;
                *(float4*)&xf[t2][s][4] = *(const float4*)(px + 4);
            }
    };

    auto process = [&](float (&xf)[2][2][8]) {
        bf16x8 af[2][2];
        #pragma unroll
        for (int t2 = 0; t2 < 2; ++t2)
            #pragma unroll
            for (int s = 0; s < 2; ++s)
                #pragma unroll
                for (int j = 0; j < 8; ++j) af[t2][s][j] = f2bf(xf[t2][s][j]);

        f32x4 acc[2][8];
        #pragma unroll
        for (int t2 = 0; t2 < 2; ++t2)
            #pragma unroll
            for (int nt = 0; nt < 8; ++nt) acc[t2][nt] = (f32x4){0.f,0.f,0.f,0.f};
        #pragma unroll
        for (int s = 0; s < 2; ++s)
            #pragma unroll
            for (int t2 = 0; t2 < 2; ++t2)
                #pragma unroll
                for (int nt = 0; nt < 8; ++nt)
                    acc[t2][nt] = __builtin_amdgcn_mfma_f32_16x16x32_bf16(
                        af[t2][s], bw[s][nt], acc[t2][nt], 0, 0, 0);

        // LN stats packed as fp16 pairs (sk,sv),(qk,qv): 2 packed reduces.
        __half2 hs[2][4], hq[2][4];
        #pragma unroll
        for (int t2 = 0; t2 < 2; ++t2)
            #pragma unroll
            for (int r = 0; r < 4; ++r) {
                float a0 = acc[t2][0][r], a1 = acc[t2][1][r], a2 = acc[t2][2][r], a3 = acc[t2][3][r];
                float b0 = acc[t2][4][r], b1 = acc[t2][5][r], b2 = acc[t2][6][r], b3 = acc[t2][7][r];
                hs[t2][r] = __floats2half2_rn((a0+a1)+(a2+a3), (b0+b1)+(b2+b3));
                hq[t2][r] = __floats2half2_rn((a0*a0+a1*a1)+(a2*a2+a3*a3),
                                              (b0*b0+b1*b1)+(b2*b2+b3*b3));
            }
        #pragma unroll
        for (int off = 1; off < 16; off <<= 1) {
            #pragma unroll
            for (int t2 = 0; t2 < 2; ++t2)
                #pragma unroll
                for (int r = 0; r < 4; ++r) {
                    int v1 = *(int*)&hs[t2][r];
                    v1 = __shfl_xor(v1, off);
                    hs[t2][r] = __hadd2(hs[t2][r], *(__half2*)&v1);
                    int v2 = *(int*)&hq[t2][r];
                    v2 = __shfl_xor(v2, off);
                    hq[t2][r] = __hadd2(hq[t2][r], *(__half2*)&v2);
                }
        }

        bf16x8 ka[4], va[4];
        #pragma unroll
        for (int t2 = 0; t2 < 2; ++t2)
            #pragma unroll
            for (int r = 0; r < 4; ++r) {
                float mk = __low2float(hs[t2][r])  * (1.f/NC);
                float mv = __high2float(hs[t2][r]) * (1.f/NC);
                float rk = rsqrtf(__low2float(hq[t2][r]) *(1.f/NC) - mk*mk + LN_EPS);
                float rv = rsqrtf(__high2float(hq[t2][r])*(1.f/NC) - mv*mv + LN_EPS);
                #pragma unroll
                for (int nt = 0; nt < 4; ++nt) {
                    // faithful: BOTH k and v normalized with lnk params
                    ka[nt][t2*4+r] = f2bf((acc[t2][nt  ][r] - mk)*rk*g[nt] + be[nt]);
                    va[nt][t2*4+r] = f2bf((acc[t2][nt+4][r] - mv)*rv*g[nt] + be[nt]);
                }
            }
        #pragma unroll
        for (int h = 0; h < 4; ++h)
            kv[h] = __builtin_amdgcn_mfma_f32_16x16x32_bf16(ka[h], va[h], kv[h], 0, 0, 0);
    };

    // software pipeline: prefetch next chunk's loads only (NCH = 8, even)
    float xfA[2][2][8], xfB[2][2][8];
    loadch(xfA, 0);
    #pragma unroll 1
    for (int ch = 0; ch < NCH; ch += 2) {
        loadch(xfB, ch + 1);
        process(xfA);
        if (ch + 2 < NCH) loadch(xfA, ch + 2);
        process(xfB);
    }

    __shared__ float red[4][1024];
    #pragma unroll
    for (int h = 0; h < 4; ++h)
        #pragma unroll
        for (int r = 0; r < 4; ++r)
            red[wave][(h*4+r)*64 + lane] = kv[h][r];
    __syncthreads();
    for (int idx = t; idx < 1024; idx += 256) {
        float s = red[0][idx] + red[1][idx] + red[2][idx] + red[3][idx];
        int ln = idx & 63, hr = idx >> 6;
        int h = hr >> 2, r = hr & 3;
        int d = (ln >> 4)*4 + r, e = ln & 15;
        atomicAdd(&xkv[(size_t)b*1024 + h*256 + d*16 + e], s);
    }
}

// -------- fold: W~[och=e*4+h][cin] = sum_d wq[cin][h*16+d]*Xkv[h][d][e]/NPIX --------
__global__ void fold_kernel(const float* __restrict__ wq,
                            const float* __restrict__ xkv,
                            short* __restrict__ wft)   // [NB][64 och][64 cin] bf16
{
    const int c4 = blockIdx.x, b = blockIdx.y, t = threadIdx.x;
    #pragma unroll
    for (int i = 0; i < 4; ++i) {
        int idx = c4*1024 + t + 256*i;
        int och = idx >> 6, c = idx & 63;
        int h = och & 3, e = och >> 2;
        float s = 0.f;
        #pragma unroll
        for (int d = 0; d < 16; ++d)
            s += wq[(size_t)b*CC + c*64 + h*16 + d] * xkv[(size_t)b*1024 + h*256 + d*16 + e];
        wft[((size_t)b*64 + och)*64 + c] = f2bf(s * (1.f/65536.f));
    }
}

// ------- pass 2: out = X · W~^T  (2-ahead rotation; LDS-transpose epilogue ->
//         full 256B rows complete per store instruction, kills L2 write
//         amplification: round 3 @8 waves/CU = 135MB vs rounds 9/12 @24-32
//         waves/CU = 192-203MB with partial-sector stores) -------
__global__ __launch_bounds__(256, 4) void q_kernel(
    const float* __restrict__ X,     // [NB][NPIX][64]
    const short* __restrict__ wft,   // [NB][64][64] bf16 ([och][cin])
    float* __restrict__ out)         // [NB][NPIX][64]
{
    const int bb = blockIdx.x, b = blockIdx.y;
    const int t = threadIdx.x, wave = t >> 6, lane = t & 63;
    const int l4 = lane >> 4, l15 = lane & 15;

    // per-wave epilogue staging tile [16 px][64 och] (4KB/wave, 16KB/block)
    __shared__ float ep[4][16][64];

    // W~ frags, reused as B-operand (k-major along j):
    // b[j] = W~^T[cin = s*32+l4*8+j][och = nt*16 + l15]  (L2-hot, loaded once)
    bf16x8 aw[2][4];
    #pragma unroll
    for (int s = 0; s < 2; ++s)
        #pragma unroll
        for (int nt = 0; nt < 4; ++nt)
            aw[s][nt] = *(const bf16x8*)&wft[((size_t)b*64 + nt*16 + l15)*64 + s*32 + l4*8];

    const size_t pixbase = (size_t)b*NPIX + (size_t)bb*QPPB + wave*QPPW;
    const float* Xw = X + pixbase*64;
    float* Ob = out + pixbase*64;

    float4 A0, A1, A2, A3, B0, B1, B2, B3, C0, C1, C2, C3;

    auto LD = [&](float4& x0, float4& x1, float4& x2, float4& x3, int tp) {
        const float* p0 = Xw + (size_t)(tp*16 + l15)*64 + l4*8;
        x0 = *(const float4*)p0;        x1 = *(const float4*)(p0 + 4);
        x2 = *(const float4*)(p0 + 32); x3 = *(const float4*)(p0 + 36);
    };
    auto PR = [&](float4& x0, float4& x1, float4& x2, float4& x3, int tp) {
        bf16x8 bx0, bx1;   // A-frags: a[j] = X[px=l15][cin = s*32 + l4*8 + j]
        #pragma unroll
        for (int j = 0; j < 4; ++j) {
            bx0[j]   = f2bf(x0[j]);  bx0[4+j] = f2bf(x1[j]);
            bx1[j]   = f2bf(x2[j]);  bx1[4+j] = f2bf(x3[j]);
        }
        f32x4 acc[4];
        #pragma unroll
        for (int nt = 0; nt < 4; ++nt) acc[nt] = (f32x4){0.f,0.f,0.f,0.f};
        // A=X, B=W~^T: D[m=px][n=och] -> lane holds px=l4*4+r, och=nt*16+l15
        #pragma unroll
        for (int nt = 0; nt < 4; ++nt)
            acc[nt] = __builtin_amdgcn_mfma_f32_16x16x32_bf16(bx0, aw[0][nt], acc[nt], 0, 0, 0);
        #pragma unroll
        for (int nt = 0; nt < 4; ++nt)
            acc[nt] = __builtin_amdgcn_mfma_f32_16x16x32_bf16(bx1, aw[1][nt], acc[nt], 0, 0, 0);
        // stage to per-wave LDS tile (same-wave RAW: lgkmcnt only, no barrier)
        #pragma unroll
        for (int nt = 0; nt < 4; ++nt)
            #pragma unroll
            for (int r = 0; r < 4; ++r)
                ep[wave][l4*4 + r][nt*16 + l15] = acc[nt][r];
        // emit 4 x dwordx4: each instruction writes 4 complete 256B rows (1KB)
        #pragma unroll
        for (int gp = 0; gp < 4; ++gp) {
            f32x4 v = *(const f32x4*)&ep[wave][gp*4 + l4][l15*4];
            *(f32x4*)&Ob[(size_t)(tp*16 + gp*4 + l4)*64 + l15*4] = v;
        }
    };

    // 8 tiles, 2-ahead static rotation: every index compile-time after inlining
    LD(A0,A1,A2,A3, 0);
    LD(B0,B1,B2,B3, 1);
    LD(C0,C1,C2,C3, 2);  PR(A0,A1,A2,A3, 0);
    LD(A0,A1,A2,A3, 3);  PR(B0,B1,B2,B3, 1);
    LD(B0,B1,B2,B3, 4);  PR(C0,C1,C2,C3, 2);
    LD(C0,C1,C2,C3, 5);  PR(A0,A1,A2,A3, 3);
    LD(A0,A1,A2,A3, 6);  PR(B0,B1,B2,B3, 4);
    LD(B0,B1,B2,B3, 7);  PR(C0,C1,C2,C3, 5);
    PR(A0,A1,A2,A3, 6);
    PR(B0,B1,B2,B3, 7);
}

extern "C" void kernel_launch(void* const* d_in, const int* in_sizes, int n_in,
                              void* d_out, int out_size, void* d_ws, size_t ws_size,
                              hipStream_t stream) {
    const float* X    = (const float*)d_in[0];
    const float* p    = (const float*)d_in[1];
    const float* qw1  = (const float*)d_in[2];
    const float* qb1  = (const float*)d_in[3];
    const float* qw2  = (const float*)d_in[4];
    const float* qb2  = (const float*)d_in[5];
    const float* kw1  = (const float*)d_in[6];
    const float* kb1  = (const float*)d_in[7];
    const float* kw2  = (const float*)d_in[8];
    const float* kb2  = (const float*)d_in[9];
    const float* vw1  = (const float*)d_in[10];
    const float* vb1  = (const float*)d_in[11];
    const float* vw2  = (const float*)d_in[12];
    const float* vb2  = (const float*)d_in[13];
    const float* lnkg = (const float*)d_in[14];
    const float* lnkb = (const float*)d_in[15];

    float* out  = (float*)d_out;
    float* wq   = (float*)d_ws;                       // NB*CC fp32
    float* xkv  = wq + (size_t)NB*CC;                 // NB*1024 fp32
    short* wkvt = (short*)(xkv + (size_t)NB*1024);    // NB*128*64 bf16
    short* wft  = wkvt + (size_t)NB*128*64;           // NB*64*64 bf16

    hyper_mlp_kernel<<<dim3(8, 3, NB), 256, 0, stream>>>(
        p, qw1,qb1,qw2,qb2, kw1,kb1,kw2,kb2, vw1,vb1,vw2,vb2, wq, wkvt, xkv);
    kv_kernel<<<dim3(BPB, NB), 256, 0, stream>>>(X, wkvt, lnkg, lnkb, xkv);
    fold_kernel<<<dim3(4, NB), 256, 0, stream>>>(wq, xkv, wft);
    q_kernel<<<dim3(QBPB, NB), 256, 0, stream>>>(X, wft, out);
}

// Round 14
// 89.133 us; speedup vs baseline: 1.5654x; 1.0262x over previous
//
#include <hip/hip_runtime.h>
#include <hip/hip_bf16.h>
#include <hip/hip_fp16.h>

typedef __attribute__((ext_vector_type(8))) short bf16x8;
typedef __attribute__((ext_vector_type(4))) float f32x4;

#define NB 8
#define NPIX 65536
#define NC 64
#define CC 4096
#define HIN 16
#define HHID 64
#define LN_EPS 1e-5f

#define BPB 64           // kv pass: 512 blocks total = exactly 2/CU, one round
#define PPBLK (NPIX/BPB) // 1024 px per kv block
#define PPW (PPBLK/4)    // 256 px per kv wave -> 8 chunks of 32
#define NCH (PPW/32)

#define QBPB 128           // q pass: 1024 blocks = exactly 4/CU, one uniform round
#define QPPB (NPIX/QBPB)   // 512 px per q block
#define QPPW (QPPB/4)      // 128 px per q wave -> 8 tiles of 16

static __device__ __forceinline__ short f2bf(float f) {
    union { __hip_bfloat16 h; short s; } u;
    u.h = __float2bfloat16(f);
    return u.s;
}

// ---------------- hypernetwork: w = (gelu(p@w1+b1))@w2 + b2 ----------------
__global__ void hyper_mlp_kernel(
    const float* __restrict__ p,
    const float* __restrict__ qw1, const float* __restrict__ qb1,
    const float* __restrict__ qw2, const float* __restrict__ qb2,
    const float* __restrict__ kw1, const float* __restrict__ kb1,
    const float* __restrict__ kw2, const float* __restrict__ kb2,
    const float* __restrict__ vw1, const float* __restrict__ vb1,
    const float* __restrict__ vw2, const float* __restrict__ vb2,
    float* __restrict__ wq,     // [NB][CC] fp32
    short* __restrict__ wkvt,   // [NB][128][64] bf16 bits
    float* __restrict__ xkv)    // [NB][1024] zeroed here
{
    const int chunk = blockIdx.x;
    const int proj  = blockIdx.y;
    const int b     = blockIdx.z;
    const float* w1 = (proj == 0) ? qw1 : (proj == 1) ? kw1 : vw1;
    const float* b1 = (proj == 0) ? qb1 : (proj == 1) ? kb1 : vb1;
    const float* w2 = (proj == 0) ? qw2 : (proj == 1) ? kw2 : vw2;
    const float* b2 = (proj == 0) ? qb2 : (proj == 1) ? kb2 : vb2;

    __shared__ float hsh[HHID];
    const int t = threadIdx.x;
    if (t < HHID) {
        float a = b1[t];
        #pragma unroll
        for (int i = 0; i < HIN; ++i) a = fmaf(p[b*HIN + i], w1[i*HHID + t], a);
        float x3 = a * a * a;
        float inner = 0.7978845608028654f * (a + 0.044715f * x3);
        hsh[t] = 0.5f * a * (1.0f + tanhf(inner));
    }
    if (proj == 1 && chunk == 0) {
        #pragma unroll
        for (int i = 0; i < 4; ++i) xkv[(size_t)b*1024 + t + 256*i] = 0.f;
    }
    __syncthreads();
    #pragma unroll
    for (int r = 0; r < 2; ++r) {
        int o = chunk*512 + t + 256*r;   // o = cin*64 + cout
        float a = b2[o];
        for (int j = 0; j < HHID; ++j) a = fmaf(hsh[j], w2[j*CC + o], a);
        int cin = o >> 6, cout = o & 63;
        if (proj == 0) {
            wq[(size_t)b*CC + o] = a;
        } else {
            int row = (proj == 1) ? cout : 64 + cout;
            wkvt[((size_t)b*128 + row)*64 + cin] = f2bf(a);
        }
    }
}

// ---------------- pass 1: K,V projection (MFMA) + LN + Xkv (MFMA) ----------------
__global__ __launch_bounds__(256, 2) void kv_kernel(
    const float* __restrict__ X,      // [NB][NPIX][64]
    const short* __restrict__ wkvt,   // [NB][128][64] bf16
    const float* __restrict__ lnk_g,
    const float* __restrict__ lnk_b,
    float* __restrict__ xkv)          // [NB][4][16][16] fp32, atomically accumulated
{
    const int bb = blockIdx.x, b = blockIdx.y;
    const int t = threadIdx.x, wave = t >> 6, lane = t & 63;
    const int l4 = lane >> 4, l15 = lane & 15;

    bf16x8 bw[2][8];
    #pragma unroll
    for (int s = 0; s < 2; ++s)
        #pragma unroll
        for (int nt = 0; nt < 8; ++nt) {
            const short* pw = wkvt + (((size_t)b*128 + nt*16 + l15)*64 + s*32 + l4*8);
            bw[s][nt] = *(const bf16x8*)pw;
        }

    float g[4], be[4];
    #pragma unroll
    for (int nt = 0; nt < 4; ++nt) {
        g[nt]  = lnk_g[nt*16 + l15];
        be[nt] = lnk_b[nt*16 + l15];
    }

    f32x4 kv[4];
    #pragma unroll
    for (int h = 0; h < 4; ++h) kv[h] = (f32x4){0.f,0.f,0.f,0.f};

    const float* Xw = X + ((size_t)b*NPIX + (size_t)bb*PPBLK + wave*PPW)*64;

    auto loadch = [&](float (&xf)[2][2][8], int ci) {
        const float* Xc = Xw + (size_t)ci*32*64;
        #pragma unroll
        for (int t2 = 0; t2 < 2; ++t2)
            #pragma unroll
            for (int s = 0; s < 2; ++s) {
                const float* px = Xc + (t2*16 + l15)*64 + s*32 + l4*8;
                *(float4*)&xf[t2][s][0] = *(const float4*)px;
                *(float4*)&xf[t2][s][4] = *(const float4*)(px + 4);
            }
    };

    auto process = [&](float (&xf)[2][2][8]) {
        bf16x8 af[2][2];
        #pragma unroll
        for (int t2 = 0; t2 < 2; ++t2)
            #pragma unroll
            for (int s = 0; s < 2; ++s)
                #pragma unroll
                for (int j = 0; j < 8; ++j) af[t2][s][j] = f2bf(xf[t2][s][j]);

        f32x4 acc[2][8];
        #pragma unroll
        for (int t2 = 0; t2 < 2; ++t2)
            #pragma unroll
            for (int nt = 0; nt < 8; ++nt) acc[t2][nt] = (f32x4){0.f,0.f,0.f,0.f};
        #pragma unroll
        for (int s = 0; s < 2; ++s)
            #pragma unroll
            for (int t2 = 0; t2 < 2; ++t2)
                #pragma unroll
                for (int nt = 0; nt < 8; ++nt)
                    acc[t2][nt] = __builtin_amdgcn_mfma_f32_16x16x32_bf16(
                        af[t2][s], bw[s][nt], acc[t2][nt], 0, 0, 0);

        // LN stats packed as fp16 pairs (sk,sv),(qk,qv): 2 packed reduces.
        __half2 hs[2][4], hq[2][4];
        #pragma unroll
        for (int t2 = 0; t2 < 2; ++t2)
            #pragma unroll
            for (int r = 0; r < 4; ++r) {
                float a0 = acc[t2][0][r], a1 = acc[t2][1][r], a2 = acc[t2][2][r], a3 = acc[t2][3][r];
                float b0 = acc[t2][4][r], b1 = acc[t2][5][r], b2 = acc[t2][6][r], b3 = acc[t2][7][r];
                hs[t2][r] = __floats2half2_rn((a0+a1)+(a2+a3), (b0+b1)+(b2+b3));
                hq[t2][r] = __floats2half2_rn((a0*a0+a1*a1)+(a2*a2+a3*a3),
                                              (b0*b0+b1*b1)+(b2*b2+b3*b3));
            }
        #pragma unroll
        for (int off = 1; off < 16; off <<= 1) {
            #pragma unroll
            for (int t2 = 0; t2 < 2; ++t2)
                #pragma unroll
                for (int r = 0; r < 4; ++r) {
                    int v1 = *(int*)&hs[t2][r];
                    v1 = __shfl_xor(v1, off);
                    hs[t2][r] = __hadd2(hs[t2][r], *(__half2*)&v1);
                    int v2 = *(int*)&hq[t2][r];
                    v2 = __shfl_xor(v2, off);
                    hq[t2][r] = __hadd2(hq[t2][r], *(__half2*)&v2);
                }
        }

        bf16x8 ka[4], va[4];
        #pragma unroll
        for (int t2 = 0; t2 < 2; ++t2)
            #pragma unroll
            for (int r = 0; r < 4; ++r) {
                float mk = __low2float(hs[t2][r])  * (1.f/NC);
                float mv = __high2float(hs[t2][r]) * (1.f/NC);
                float rk = rsqrtf(__low2float(hq[t2][r]) *(1.f/NC) - mk*mk + LN_EPS);
                float rv = rsqrtf(__high2float(hq[t2][r])*(1.f/NC) - mv*mv + LN_EPS);
                #pragma unroll
                for (int nt = 0; nt < 4; ++nt) {
                    // faithful: BOTH k and v normalized with lnk params
                    ka[nt][t2*4+r] = f2bf((acc[t2][nt  ][r] - mk)*rk*g[nt] + be[nt]);
                    va[nt][t2*4+r] = f2bf((acc[t2][nt+4][r] - mv)*rv*g[nt] + be[nt]);
                }
            }
        #pragma unroll
        for (int h = 0; h < 4; ++h)
            kv[h] = __builtin_amdgcn_mfma_f32_16x16x32_bf16(ka[h], va[h], kv[h], 0, 0, 0);
    };

    // software pipeline: prefetch next chunk's loads only (NCH = 8, even)
    float xfA[2][2][8], xfB[2][2][8];
    loadch(xfA, 0);
    #pragma unroll 1
    for (int ch = 0; ch < NCH; ch += 2) {
        loadch(xfB, ch + 1);
        process(xfA);
        if (ch + 2 < NCH) loadch(xfA, ch + 2);
        process(xfB);
    }

    __shared__ float red[4][1024];
    #pragma unroll
    for (int h = 0; h < 4; ++h)
        #pragma unroll
        for (int r = 0; r < 4; ++r)
            red[wave][(h*4+r)*64 + lane] = kv[h][r];
    __syncthreads();
    for (int idx = t; idx < 1024; idx += 256) {
        float s = red[0][idx] + red[1][idx] + red[2][idx] + red[3][idx];
        int ln = idx & 63, hr = idx >> 6;
        int h = hr >> 2, r = hr & 3;
        int d = (ln >> 4)*4 + r, e = ln & 15;
        atomicAdd(&xkv[(size_t)b*1024 + h*256 + d*16 + e], s);
    }
}

// -------- fold: W~[och=e*4+h][cin] = sum_d wq[cin][h*16+d]*Xkv[h][d][e]/NPIX --------
__global__ void fold_kernel(const float* __restrict__ wq,
                            const float* __restrict__ xkv,
                            short* __restrict__ wft)   // [NB][64 och][64 cin] bf16
{
    const int c4 = blockIdx.x, b = blockIdx.y, t = threadIdx.x;
    #pragma unroll
    for (int i = 0; i < 4; ++i) {
        int idx = c4*1024 + t + 256*i;
        int och = idx >> 6, c = idx & 63;
        int h = och & 3, e = och >> 2;
        float s = 0.f;
        #pragma unroll
        for (int d = 0; d < 16; ++d)
            s += wq[(size_t)b*CC + c*64 + h*16 + d] * xkv[(size_t)b*1024 + h*256 + d*16 + e];
        wft[((size_t)b*64 + och)*64 + c] = f2bf(s * (1.f/65536.f));
    }
}

// ------- pass 2: out = X · W~^T  (2-ahead rotation; LDS-transpose epilogue
//         emits 1KB-contiguous full-line stores, now NONTEMPORAL so out does
//         not allocate in L2/L3 -> X stays L3-resident for q's reads.
//         (NT is safe here: full lines per instruction, no partial-line RMW;
//          round-8's NT blowup was 16B/lane scattered stores.) -------
__global__ __launch_bounds__(256, 4) void q_kernel(
    const float* __restrict__ X,     // [NB][NPIX][64]
    const short* __restrict__ wft,   // [NB][64][64] bf16 ([och][cin])
    float* __restrict__ out)         // [NB][NPIX][64]
{
    const int bb = blockIdx.x, b = blockIdx.y;
    const int t = threadIdx.x, wave = t >> 6, lane = t & 63;
    const int l4 = lane >> 4, l15 = lane & 15;

    // per-wave epilogue staging tile [16 px][64 och] (4KB/wave, 16KB/block)
    __shared__ float ep[4][16][64];

    // W~ frags, reused as B-operand (k-major along j):
    // b[j] = W~^T[cin = s*32+l4*8+j][och = nt*16 + l15]  (L2-hot, loaded once)
    bf16x8 aw[2][4];
    #pragma unroll
    for (int s = 0; s < 2; ++s)
        #pragma unroll
        for (int nt = 0; nt < 4; ++nt)
            aw[s][nt] = *(const bf16x8*)&wft[((size_t)b*64 + nt*16 + l15)*64 + s*32 + l4*8];

    const size_t pixbase = (size_t)b*NPIX + (size_t)bb*QPPB + wave*QPPW;
    const float* Xw = X + pixbase*64;
    float* Ob = out + pixbase*64;

    float4 A0, A1, A2, A3, B0, B1, B2, B3, C0, C1, C2, C3;

    auto LD = [&](float4& x0, float4& x1, float4& x2, float4& x3, int tp) {
        const float* p0 = Xw + (size_t)(tp*16 + l15)*64 + l4*8;
        x0 = *(const float4*)p0;        x1 = *(const float4*)(p0 + 4);
        x2 = *(const float4*)(p0 + 32); x3 = *(const float4*)(p0 + 36);
    };
    auto PR = [&](float4& x0, float4& x1, float4& x2, float4& x3, int tp) {
        bf16x8 bx0, bx1;   // A-frags: a[j] = X[px=l15][cin = s*32 + l4*8 + j]
        #pragma unroll
        for (int j = 0; j < 4; ++j) {
            bx0[j]   = f2bf(x0[j]);  bx0[4+j] = f2bf(x1[j]);
            bx1[j]   = f2bf(x2[j]);  bx1[4+j] = f2bf(x3[j]);
        }
        f32x4 acc[4];
        #pragma unroll
        for (int nt = 0; nt < 4; ++nt) acc[nt] = (f32x4){0.f,0.f,0.f,0.f};
        // A=X, B=W~^T: D[m=px][n=och] -> lane holds px=l4*4+r, och=nt*16+l15
        #pragma unroll
        for (int nt = 0; nt < 4; ++nt)
            acc[nt] = __builtin_amdgcn_mfma_f32_16x16x32_bf16(bx0, aw[0][nt], acc[nt], 0, 0, 0);
        #pragma unroll
        for (int nt = 0; nt < 4; ++nt)
            acc[nt] = __builtin_amdgcn_mfma_f32_16x16x32_bf16(bx1, aw[1][nt], acc[nt], 0, 0, 0);
        // stage to per-wave LDS tile (same-wave RAW: lgkmcnt only, no barrier)
        #pragma unroll
        for (int nt = 0; nt < 4; ++nt)
            #pragma unroll
            for (int r = 0; r < 4; ++r)
                ep[wave][l4*4 + r][nt*16 + l15] = acc[nt][r];
        // emit 4 x dwordx4 NT: each instruction writes 4 complete 256B rows (1KB)
        #pragma unroll
        for (int gp = 0; gp < 4; ++gp) {
            f32x4 v = *(const f32x4*)&ep[wave][gp*4 + l4][l15*4];
            __builtin_nontemporal_store(v,
                (f32x4*)&Ob[(size_t)(tp*16 + gp*4 + l4)*64 + l15*4]);
        }
    };

    // 8 tiles, 2-ahead static rotation: every index compile-time after inlining
    LD(A0,A1,A2,A3, 0);
    LD(B0,B1,B2,B3, 1);
    LD(C0,C1,C2,C3, 2);  PR(A0,A1,A2,A3, 0);
    LD(A0,A1,A2,A3, 3);  PR(B0,B1,B2,B3, 1);
    LD(B0,B1,B2,B3, 4);  PR(C0,C1,C2,C3, 2);
    LD(C0,C1,C2,C3, 5);  PR(A0,A1,A2,A3, 3);
    LD(A0,A1,A2,A3, 6);  PR(B0,B1,B2,B3, 4);
    LD(B0,B1,B2,B3, 7);  PR(C0,C1,C2,C3, 5);
    PR(A0,A1,A2,A3, 6);
    PR(B0,B1,B2,B3, 7);
}

extern "C" void kernel_launch(void* const* d_in, const int* in_sizes, int n_in,
                              void* d_out, int out_size, void* d_ws, size_t ws_size,
                              hipStream_t stream) {
    const float* X    = (const float*)d_in[0];
    const float* p    = (const float*)d_in[1];
    const float* qw1  = (const float*)d_in[2];
    const float* qb1  = (const float*)d_in[3];
    const float* qw2  = (const float*)d_in[4];
    const float* qb2  = (const float*)d_in[5];
    const float* kw1  = (const float*)d_in[6];
    const float* kb1  = (const float*)d_in[7];
    const float* kw2  = (const float*)d_in[8];
    const float* kb2  = (const float*)d_in[9];
    const float* vw1  = (const float*)d_in[10];
    const float* vb1  = (const float*)d_in[11];
    const float* vw2  = (const float*)d_in[12];
    const float* vb2  = (const float*)d_in[13];
    const float* lnkg = (const float*)d_in[14];
    const float* lnkb = (const float*)d_in[15];

    float* out  = (float*)d_out;
    float* wq   = (float*)d_ws;                       // NB*CC fp32
    float* xkv  = wq + (size_t)NB*CC;                 // NB*1024 fp32
    short* wkvt = (short*)(xkv + (size_t)NB*1024);    // NB*128*64 bf16
    short* wft  = wkvt + (size_t)NB*128*64;           // NB*64*64 bf16

    hyper_mlp_kernel<<<dim3(8, 3, NB), 256, 0, stream>>>(
        p, qw1,qb1,qw2,qb2, kw1,kb1,kw2,kb2, vw1,vb1,vw2,vb2, wq, wkvt, xkv);
    kv_kernel<<<dim3(BPB, NB), 256, 0, stream>>>(X, wkvt, lnkg, lnkb, xkv);
    fold_kernel<<<dim3(4, NB), 256, 0, stream>>>(wq, xkv, wft);
    q_kernel<<<dim3(QBPB, NB), 256, 0, stream>>>(X, wft, out);
}